// Round 21
// baseline (343.118 us; speedup 1.0000x reference)
//
#include <hip/hip_runtime.h>

typedef __bf16 bf16;
typedef __attribute__((ext_vector_type(8))) __bf16 bf16x8;
typedef __attribute__((ext_vector_type(4))) float f32x4;

#define B_SZ 4
#define SEQ 2048
#define DM 1024
#define DIN 2048
#define NH 256
#define DSTATE 16
#define CONVD 2080
#define DPROJ 4384
#define NPAD1 4608
#define MROWS 8192
#define NC 32
#define LC 64
#define UROWB 8768  // u row stride in bytes (4384 * 2)

__device__ __forceinline__ void gload_lds16(const void* g, void* l) {
  __builtin_amdgcn_global_load_lds(
      (__attribute__((address_space(1))) void*)g,
      (__attribute__((address_space(3))) void*)l, 16, 0, 0);
}

template <int N>
__device__ __forceinline__ void vm_wait() {
  asm volatile("s_waitcnt vmcnt(%0)" ::"n"(N) : "memory");
}
__device__ __forceinline__ void bar() { asm volatile("s_barrier" ::: "memory"); }
__device__ __forceinline__ void lgkm0() {
  asm volatile("s_waitcnt lgkmcnt(0)" ::: "memory");
}

// ---------------- both weight transposes in one launch (z selects which)
__global__ void transpose_both(const float* __restrict__ W0, bf16* __restrict__ T0,
                               const float* __restrict__ W1, bf16* __restrict__ T1,
                               const float* __restrict__ rw1) {
  const float* W; bf16* WT; int K, N, Npad; const float* rw;
  if (blockIdx.z == 0) { W = W0; WT = T0; K = 1024; N = DPROJ; Npad = NPAD1; rw = nullptr; }
  else { W = W1; WT = T1; K = DIN; N = DM; Npad = DM; rw = rw1; }
  int k0 = blockIdx.x * 32, n0 = blockIdx.y * 32;
  if (k0 >= K || n0 >= Npad) return;  // block-uniform exit, no sync hazard
  __shared__ float tile[32][33];
  int tx = threadIdx.x, ty = threadIdx.y;  // (32, 8)
#pragma unroll
  for (int j = 0; j < 4; j++) {
    int k = k0 + ty + 8 * j, n = n0 + tx;
    float v = (k < K && n < N) ? W[(size_t)k * N + n] : 0.f;
    if (rw && k < K) v *= rw[k];
    tile[ty + 8 * j][tx] = v;
  }
  __syncthreads();
#pragma unroll
  for (int j = 0; j < 4; j++) {
    int n = n0 + ty + 8 * j, k = k0 + tx;
    if (n < Npad && k < K) WT[(size_t)n * K + k] = (bf16)tile[tx][ty + 8 * j];
  }
}

// ---------------- layernorm (f32 in) -> xn bf16
__global__ __launch_bounds__(256) void ln_kernel(const float* __restrict__ x,
                                                 const float* __restrict__ lw,
                                                 const float* __restrict__ lb,
                                                 bf16* __restrict__ xn) {
  int row = blockIdx.x;
  int t = threadIdx.x;
  f32x4 v4 = ((const f32x4*)(x + (size_t)row * DM))[t];
  float v0 = v4[0], v1 = v4[1], v2 = v4[2], v3 = v4[3];
  float s = v0 + v1 + v2 + v3;
  float s2 = v0 * v0 + v1 * v1 + v2 * v2 + v3 * v3;
#pragma unroll
  for (int off = 32; off > 0; off >>= 1) {
    s += __shfl_down(s, off);
    s2 += __shfl_down(s2, off);
  }
  __shared__ float ps[8];
  int wave = t >> 6, lane = t & 63;
  if (lane == 0) { ps[wave] = s; ps[4 + wave] = s2; }
  __syncthreads();
  s = ps[0] + ps[1] + ps[2] + ps[3];
  s2 = ps[4] + ps[5] + ps[6] + ps[7];
  float mean = s * (1.f / DM);
  float var = s2 * (1.f / DM) - mean * mean;
  float rstd = rsqrtf(var + 1e-5f);
  f32x4 wv = ((const f32x4*)lw)[t];
  f32x4 bv = ((const f32x4*)lb)[t];
  bf16 o[4];
  o[0] = (bf16)((v0 - mean) * rstd * wv[0] + bv[0]);
  o[1] = (bf16)((v1 - mean) * rstd * wv[1] + bv[1]);
  o[2] = (bf16)((v2 - mean) * rstd * wv[2] + bv[2]);
  o[3] = (bf16)((v3 - mean) * rstd * wv[3] + bv[3]);
  bf16* dst = xn + (size_t)row * DM + t * 4;
  dst[0] = o[0]; dst[1] = o[1]; dst[2] = o[2]; dst[3] = o[3];
}

// ---------------- GEMM1: 128x192 tile, grid 1536 (= 3 rounds at 2 blocks/CU), BK=64,
// 8 waves (2M x 4N, wave 64x48). LDS 80KB -> 2 blocks/CU (m114 inter-block overlap).
__global__ __launch_bounds__(512, 2) void gemm1_8p(const bf16* __restrict__ A,
                                                   const bf16* __restrict__ BT,
                                                   bf16* __restrict__ C) {
  __shared__ char lds[81920];
  int bid = blockIdx.x;  // 1536 = 64 m-tiles * 24 n-tiles
  int xcd = bid & 7;
  int l = bid >> 3;             // 0..191
  int bm = xcd * 8 + (l & 7);
  int bn = l >> 3;
  int m0 = bm * 128, n0 = bn * 192;
  int t = threadIdx.x, lane = t & 63, wave = t >> 6;
  int wm = wave >> 2, wn = wave & 3;
  int lr16 = lane & 15, kq = lane >> 4;
  int ts0 = kq ^ (lr16 & 7);
  int ts1 = (4 + kq) ^ (lr16 & 7);
  int sw = (lane & 7) ^ (lane >> 3);
  int l8 = lane >> 3;
  const char* Ab = (const char*)A;
  const char* Bb = (const char*)BT;

  auto stA = [&](int kt) {
    char* slot = lds + (kt & 1) * 16384;
    size_t ko = (size_t)kt * 128 + sw * 16;
#pragma unroll
    for (int g = 0; g < 2; g++) {
      int c = wave * 2 + g;
      gload_lds16(Ab + (size_t)(m0 + c * 8 + l8) * 2048 + ko, slot + c * 1024);
    }
  };
  auto stB = [&](int kt) {
    char* slot = lds + 32768 + (kt & 1) * 24576;
    size_t ko = (size_t)kt * 128 + sw * 16;
#pragma unroll
    for (int g = 0; g < 3; g++) {
      int c = wave * 3 + g;
      gload_lds16(Bb + (size_t)(n0 + c * 8 + l8) * 2048 + ko, slot + c * 1024);
    }
  };

  f32x4 acc[4][3] = {};
  bf16x8 a_[2][2], b_[3][2];

  stA(0); stB(0); stA(1); stB(1);
  vm_wait<5>();
  bar();
#pragma unroll 1
  for (int kt = 0; kt < 16; kt++) {
    const char* sa = lds + (kt & 1) * 16384;
    const char* sb = lds + 32768 + (kt & 1) * 24576;
    {
#pragma unroll
      for (int mi = 0; mi < 2; mi++) {
        int lrow = wm * 64 + mi * 16 + lr16;
        a_[mi][0] = *(const bf16x8*)(sa + lrow * 128 + ts0 * 16);
        a_[mi][1] = *(const bf16x8*)(sa + lrow * 128 + ts1 * 16);
      }
#pragma unroll
      for (int ni = 0; ni < 3; ni++) {
        int lrow = wn * 48 + ni * 16 + lr16;
        b_[ni][0] = *(const bf16x8*)(sb + lrow * 128 + ts0 * 16);
        b_[ni][1] = *(const bf16x8*)(sb + lrow * 128 + ts1 * 16);
      }
      if (kt >= 1 && kt < 15) { stA(kt + 1); stB(kt + 1); }
      bar();
      lgkm0();
      __builtin_amdgcn_s_setprio(1);
#pragma unroll
      for (int mi = 0; mi < 2; mi++)
#pragma unroll
        for (int ni = 0; ni < 3; ni++) {
          acc[mi][ni] = __builtin_amdgcn_mfma_f32_16x16x32_bf16(a_[mi][0], b_[ni][0], acc[mi][ni], 0, 0, 0);
          acc[mi][ni] = __builtin_amdgcn_mfma_f32_16x16x32_bf16(a_[mi][1], b_[ni][1], acc[mi][ni], 0, 0, 0);
        }
      __builtin_amdgcn_s_setprio(0);
      bar();
    }
    {
#pragma unroll
      for (int mi = 0; mi < 2; mi++) {
        int lrow = wm * 64 + (2 + mi) * 16 + lr16;
        a_[mi][0] = *(const bf16x8*)(sa + lrow * 128 + ts0 * 16);
        a_[mi][1] = *(const bf16x8*)(sa + lrow * 128 + ts1 * 16);
      }
      if (kt < 15) vm_wait<0>();
      bar();
      lgkm0();
      __builtin_amdgcn_s_setprio(1);
#pragma unroll
      for (int mi = 0; mi < 2; mi++)
#pragma unroll
        for (int ni = 0; ni < 3; ni++) {
          acc[2 + mi][ni] = __builtin_amdgcn_mfma_f32_16x16x32_bf16(a_[mi][0], b_[ni][0], acc[2 + mi][ni], 0, 0, 0);
          acc[2 + mi][ni] = __builtin_amdgcn_mfma_f32_16x16x32_bf16(a_[mi][1], b_[ni][1], acc[2 + mi][ni], 0, 0, 0);
        }
      __builtin_amdgcn_s_setprio(0);
      bar();
    }
  }
#pragma unroll
  for (int fr = 0; fr < 4; fr++)
#pragma unroll
    for (int ni = 0; ni < 3; ni++) {
      int row = m0 + wm * 64 + fr * 16 + kq * 4;
      int col = n0 + wn * 48 + ni * 16 + lr16;
      f32x4 v = acc[fr][ni];
      if (col < 4384) {
#pragma unroll
        for (int r = 0; r < 4; r++)
          C[(size_t)(row + r) * DPROJ + col] = (bf16)v[r];
      }
    }
}

// ---------------- GEMM2: 128x256 tile, BK=64, 8 waves (2M x 4N), grid 256.
// A = g_raw; fused RMSNorm (rms_w folded into WoutT; s2 from A-fragments).
__global__ __launch_bounds__(512, 2) void gemm2_8p(const bf16* __restrict__ A,
                                                   const bf16* __restrict__ BT,
                                                   float* __restrict__ C,
                                                   const float* __restrict__ Xres) {
  __shared__ char lds[147456];
  int bid = blockIdx.x;                  // 256 = 64 m * 4 n
  int swz = (bid & 7) * 32 + (bid >> 3); // bijective (256 % 8 == 0)
  int bm = swz >> 2, bn = swz & 3;
  int m0 = bm * 128, n0 = bn * 256;
  int t = threadIdx.x, lane = t & 63, wave = t >> 6;
  int wm = wave >> 2, wn = wave & 3;
  int lr16 = lane & 15, kq = lane >> 4;
  int ts0 = kq ^ (lr16 & 7);
  int ts1 = (4 + kq) ^ (lr16 & 7);
  int sw = (lane & 7) ^ (lane >> 3);
  int l8 = lane >> 3;
  const char* Ab = (const char*)A;
  const char* Bb = (const char*)BT;

  auto stA = [&](int kt) {
    char* slot = lds + (kt % 3) * 16384;
    size_t ko = (size_t)kt * 128 + sw * 16;
#pragma unroll
    for (int g = 0; g < 2; g++) {
      int c = wave * 2 + g;
      gload_lds16(Ab + (size_t)(m0 + c * 8 + l8) * 4096 + ko, slot + c * 1024);
    }
  };
  auto stB = [&](int kt) {
    char* slot = lds + 49152 + (kt % 3) * 32768;
    size_t ko = (size_t)kt * 128 + sw * 16;
#pragma unroll
    for (int g = 0; g < 4; g++) {
      int c = wave * 4 + g;
      gload_lds16(Bb + (size_t)(n0 + c * 8 + l8) * 4096 + ko, slot + c * 1024);
    }
  };

  f32x4 acc[4][4] = {};
  bf16x8 a_[4][2], b_[2][2];
  float s2a[4] = {0.f, 0.f, 0.f, 0.f};

  stA(0); stB(0); stA(1); stB(1);
  vm_wait<6>();
  bar();
#pragma unroll 1
  for (int kt = 0; kt < 32; kt++) {
    const char* sa = lds + (kt % 3) * 16384;
    const char* sb = lds + 49152 + (kt % 3) * 32768;
    {
#pragma unroll
      for (int mi = 0; mi < 4; mi++) {
        int lrow = wm * 64 + mi * 16 + lr16;
        a_[mi][0] = *(const bf16x8*)(sa + lrow * 128 + ts0 * 16);
        a_[mi][1] = *(const bf16x8*)(sa + lrow * 128 + ts1 * 16);
      }
#pragma unroll
      for (int ni = 0; ni < 2; ni++) {
        int lrow = wn * 64 + ni * 16 + lr16;
        b_[ni][0] = *(const bf16x8*)(sb + lrow * 128 + ts0 * 16);
        b_[ni][1] = *(const bf16x8*)(sb + lrow * 128 + ts1 * 16);
      }
      if (kt + 2 < 32) { stA(kt + 2); stB(kt + 2); }
      bar();
      lgkm0();
      __builtin_amdgcn_s_setprio(1);
#pragma unroll
      for (int mi = 0; mi < 4; mi++)
#pragma unroll
        for (int ni = 0; ni < 2; ni++) {
          acc[mi][ni] = __builtin_amdgcn_mfma_f32_16x16x32_bf16(a_[mi][0], b_[ni][0], acc[mi][ni], 0, 0, 0);
          acc[mi][ni] = __builtin_amdgcn_mfma_f32_16x16x32_bf16(a_[mi][1], b_[ni][1], acc[mi][ni], 0, 0, 0);
        }
      __builtin_amdgcn_s_setprio(0);
      bar();
    }
    {
#pragma unroll
      for (int ni = 0; ni < 2; ni++) {
        int lrow = wn * 64 + (2 + ni) * 16 + lr16;
        b_[ni][0] = *(const bf16x8*)(sb + lrow * 128 + ts0 * 16);
        b_[ni][1] = *(const bf16x8*)(sb + lrow * 128 + ts1 * 16);
      }
      if (kt <= 29) vm_wait<6>();
      else if (kt == 30) vm_wait<0>();
      bar();
      lgkm0();
      __builtin_amdgcn_s_setprio(1);
#pragma unroll
      for (int mi = 0; mi < 4; mi++)
#pragma unroll
        for (int ni = 0; ni < 2; ni++) {
          acc[mi][2 + ni] = __builtin_amdgcn_mfma_f32_16x16x32_bf16(a_[mi][0], b_[ni][0], acc[mi][2 + ni], 0, 0, 0);
          acc[mi][2 + ni] = __builtin_amdgcn_mfma_f32_16x16x32_bf16(a_[mi][1], b_[ni][1], acc[mi][2 + ni], 0, 0, 0);
        }
      __builtin_amdgcn_s_setprio(0);
#pragma unroll
      for (int mi = 0; mi < 4; mi++) {
        float s = 0.f;
#pragma unroll
        for (int si = 0; si < 2; si++)
#pragma unroll
          for (int e = 0; e < 8; e++) {
            float v = (float)a_[mi][si][e];
            s += v * v;
          }
        s2a[mi] += s;
      }
      bar();
    }
  }
#pragma unroll
  for (int mi = 0; mi < 4; mi++) {
    s2a[mi] += __shfl_xor(s2a[mi], 16);
    s2a[mi] += __shfl_xor(s2a[mi], 32);
  }
  float* scaleL = (float*)lds;
  if (wn == 0 && kq == 0) {
#pragma unroll
    for (int mi = 0; mi < 4; mi++)
      scaleL[wm * 64 + mi * 16 + lr16] = rsqrtf(s2a[mi] * (1.f / 2048.f) + 1e-5f);
  }
  __syncthreads();
#pragma unroll
  for (int mi = 0; mi < 4; mi++)
#pragma unroll
    for (int ni = 0; ni < 4; ni++) {
      int rloc = wm * 64 + mi * 16 + kq * 4;
      int col = n0 + wn * 64 + ni * 16 + lr16;
      f32x4 v = acc[mi][ni];
#pragma unroll
      for (int r = 0; r < 4; r++) {
        float sc = scaleL[rloc + r];
        size_t o = (size_t)(m0 + rloc + r) * DM + col;
        C[o] = Xres[o] + sc * v[r];
      }
    }
}

// ---------------- conv: one thread per 8-channel vector per row (wide precompute)
__global__ __launch_bounds__(256) void conv_prep3(const bf16* __restrict__ u,
                                                  const float* __restrict__ cw,
                                                  const float* __restrict__ cb,
                                                  const float* __restrict__ dt_bias,
                                                  bf16* __restrict__ xs,
                                                  float* __restrict__ BC,
                                                  float* __restrict__ dtf) {
  const int JPR = 292;  // 260 conv vec8 + 32 dt vec8
  int idx = blockIdx.x * 256 + threadIdx.x;
  if (idx >= MROWS * JPR) return;
  int row = idx / JPR;
  int j = idx - row * JPR;
  int t = row & (SEQ - 1);
  if (j < 260) {
    int c0 = j * 8;
    float acc[8];
#pragma unroll
    for (int i = 0; i < 8; i++) acc[i] = cb[c0 + i];
    const bf16* ub = u + (size_t)row * DPROJ + DIN + c0;
#pragma unroll
    for (int tap = 0; tap < 4; tap++) {
      int tt = t - 3 + tap;
      if (tt >= 0) {
        bf16x8 uv = *(const bf16x8*)(ub + (ptrdiff_t)(tap - 3) * DPROJ);
        const float* wv = cw + tap * CONVD + c0;
#pragma unroll
        for (int i = 0; i < 8; i++) acc[i] += wv[i] * (float)uv[i];
      }
    }
    if (c0 < DIN) {
      bf16x8 o;
#pragma unroll
      for (int i = 0; i < 8; i++) {
        float sv = acc[i] / (1.f + __expf(-acc[i]));
        o[i] = (bf16)sv;
      }
      *(bf16x8*)(xs + (size_t)row * DIN + c0) = o;
    } else {
      float* bc = BC + (size_t)row * 32 + (c0 - DIN);
#pragma unroll
      for (int i = 0; i < 8; i++) bc[i] = acc[i] / (1.f + __expf(-acc[i]));
    }
  } else {
    int h0 = (j - 260) * 8;
    bf16x8 uv = *(const bf16x8*)(u + (size_t)row * DPROJ + (DPROJ - NH) + h0);
    float* dst = dtf + (size_t)row * NH + h0;
#pragma unroll
    for (int i = 0; i < 8; i++) {
      float xv = (float)uv[i] + dt_bias[h0 + i];
      dst[i] = (xv > 20.f) ? xv : log1pf(__expf(xv));
    }
  }
}

// ---------------- chunked scan (LC=64, NC=32), phase 1: local scan -> (S, P) in u tail
// 256-thr blocks = 4 independent waves; wave w owns unit = blockIdx.x*4+w
__global__ __launch_bounds__(256) void scan_p1(const bf16* __restrict__ xs,
                                               const float* __restrict__ BC,
                                               const float* __restrict__ dtf,
                                               const float* __restrict__ A_log,
                                               bf16* __restrict__ uscr) {
  int wave = threadIdx.x >> 6;
  int unit = blockIdx.x * 4 + wave;  // 0..4095
  int c = unit & 31, hg = (unit >> 5) & 31, b = unit >> 10;
  int lane = threadIdx.x & 63, hh = lane >> 3;
  int h = hg * 8 + hh;
  float A = -__expf(A_log[h]);
  float st[16];
#pragma unroll
  for (int n = 0; n < 16; n++) st[n] = 0.f;
  float pcum = 1.f;
  size_t rb = (size_t)b * SEQ + (size_t)c * LC;
#pragma unroll 2
  for (int t = 0; t < LC; t++) {
    size_t row = rb + t;
    const float* bcrow = BC + row * 32;
    float dtv = dtf[row * NH + h];
    float x = (float)xs[row * DIN + hg * 64 + lane];
    float dA = __expf(dtv * A);
    pcum *= dA;
    float w = dtv * x;
#pragma unroll
    for (int n = 0; n < 16; n++) st[n] = st[n] * dA + w * bcrow[n];
  }
  char* slot = (char*)uscr + (size_t)unit * UROWB + 4096;
  float* S = (float*)slot;
#pragma unroll
  for (int n = 0; n < 16; n++) S[lane * 16 + n] = st[n];
  if ((lane & 7) == 0) ((float*)(slot + 4096))[hh] = pcum;
}

// ---------------- phase 2: sequential combine over 32 chunks; S <- incoming H
__global__ __launch_bounds__(64) void scan_p2(bf16* __restrict__ uscr) {
  int bh = blockIdx.x;  // 0..127 = b*32+hg
  int lane = threadIdx.x, hh = lane >> 3;
  float H[16];
#pragma unroll
  for (int n = 0; n < 16; n++) H[n] = 0.f;
  char* base = (char*)uscr + (size_t)bh * NC * UROWB + 4096;
  float sN[16], PN;
  {
    float* S = (float*)base;
#pragma unroll
    for (int n = 0; n < 16; n++) sN[n] = S[lane * 16 + n];
    PN = ((const float*)(base + 4096))[hh];
  }
  for (int c = 0; c < NC; c++) {
    float sC[16], PC = PN;
#pragma unroll
    for (int n = 0; n < 16; n++) sC[n] = sN[n];
    if (c + 1 < NC) {
      char* slot = base + (size_t)(c + 1) * UROWB;
      float* S = (float*)slot;
#pragma unroll
      for (int n = 0; n < 16; n++) sN[n] = S[lane * 16 + n];
      PN = ((const float*)(slot + 4096))[hh];
    }
    float* S0 = (float*)(base + (size_t)c * UROWB);
#pragma unroll
    for (int n = 0; n < 16; n++) {
      float hn = H[n];
      S0[lane * 16 + n] = hn;
      H[n] = PC * hn + sC[n];
    }
  }
}

// ---------------- phase 3 (fused gate): re-scan chunk, g_raw = (yv + D*x)*silu(z)
// 256-thr blocks = 4 independent waves
__global__ __launch_bounds__(256) void scan_p3(const bf16* __restrict__ xs,
                                               const float* __restrict__ BC,
                                               const float* __restrict__ dtf,
                                               const float* __restrict__ A_log,
                                               const float* __restrict__ Dp,
                                               const bf16* __restrict__ u,
                                               bf16* __restrict__ g) {
  int wave = threadIdx.x >> 6;
  int unit = blockIdx.x * 4 + wave;  // 0..4095
  int c = unit & 31, hg = (unit >> 5) & 31, b = unit >> 10;
  int lane = threadIdx.x & 63, hh = lane >> 3;
  int h = hg * 8 + hh;
  float A = -__expf(A_log[h]);
  float D = Dp[h];
  const char* slot = (const char*)u + (size_t)unit * UROWB + 4096;
  float st[16];
#pragma unroll
  for (int n = 0; n < 16; n++) st[n] = ((const float*)slot)[lane * 16 + n];
  size_t rb = (size_t)b * SEQ + (size_t)c * LC;
#pragma unroll 2
  for (int t = 0; t < LC; t++) {
    size_t row = rb + t;
    const float* bcrow = BC + row * 32;
    float dtv = dtf[row * NH + h];
    float x = (float)xs[row * DIN + hg * 64 + lane];
    float dA = __expf(dtv * A);
    float w = dtv * x;
    float yv = 0.f;
#pragma unroll
    for (int n = 0; n < 16; n++) {
      st[n] = st[n] * dA + w * bcrow[n];
      yv += st[n] * bcrow[16 + n];
    }
    float z = (float)u[row * DPROJ + hg * 64 + lane];
    float gg = (yv + D * x) * (z / (1.f + __expf(-z)));
    g[row * DIN + hg * 64 + lane] = (bf16)gg;
  }
}

extern "C" void kernel_launch(void* const* d_in, const int* in_sizes, int n_in,
                              void* d_out, int out_size, void* d_ws, size_t ws_size,
                              hipStream_t stream) {
  const float* x = (const float*)d_in[0];
  const float* lnw = (const float*)d_in[1];
  const float* lnb = (const float*)d_in[2];
  const float* Win = (const float*)d_in[3];
  const float* cw = (const float*)d_in[4];
  const float* cb = (const float*)d_in[5];
  const float* Alog = (const float*)d_in[6];
  const float* Dpv = (const float*)d_in[7];
  const float* dtb = (const float*)d_in[8];
  const float* rmsw = (const float*)d_in[9];
  const float* Wout = (const float*)d_in[10];
  float* out = (float*)d_out;

  char* ws = (char*)d_ws;
  bf16* u = (bf16*)(ws + 0);                     // [8192][4384] bf16
  bf16* xnb = (bf16*)(ws + 71827456);            // [8192][1024] bf16 (dead after GEMM1)
  bf16* WinT = (bf16*)(ws + 88604672);           // [4608][1024] bf16 (dead after GEMM1)
  bf16* gb = (bf16*)(ws + 71827456);             // [8192][2048] bf16 g_raw (reuses xnb+WinT)
  bf16* xsb = (bf16*)(ws + 105381888);           // [8192][2048] bf16
  float* BC = (float*)(ws + 138936320);          // [8192][32] f32
  float* dtf = (float*)(ws + 139984896);         // [8192][256] f32
  bf16* WoutT = (bf16*)(ws + 148373504);         // [1024][2048] bf16 (rms_w folded)

  transpose_both<<<dim3(64, 144, 2), dim3(32, 8), 0, stream>>>(Win, WinT, Wout, WoutT, rmsw);
  ln_kernel<<<MROWS, 256, 0, stream>>>(x, lnw, lnb, xnb);
  gemm1_8p<<<1536, 512, 0, stream>>>(xnb, WinT, u);
  conv_prep3<<<(MROWS * 292) / 256, 256, 0, stream>>>(u, cw, cb, dtb, xsb, BC, dtf);
  scan_p1<<<1024, 256, 0, stream>>>(xsb, BC, dtf, Alog, u);
  scan_p2<<<128, 64, 0, stream>>>(u);
  scan_p3<<<1024, 256, 0, stream>>>(xsb, BC, dtf, Alog, Dpv, u, gb);
  gemm2_8p<<<256, 512, 0, stream>>>(gb, WoutT, out, x);
}

// Round 22
// 277.405 us; speedup vs baseline: 1.2369x; 1.2369x over previous
//
#include <hip/hip_runtime.h>

typedef __bf16 bf16;
typedef __attribute__((ext_vector_type(8))) __bf16 bf16x8;
typedef __attribute__((ext_vector_type(4))) float f32x4;

#define B_SZ 4
#define SEQ 2048
#define DM 1024
#define DIN 2048
#define NH 256
#define DSTATE 16
#define CONVD 2080
#define DPROJ 4384
#define NPAD1 4608
#define MROWS 8192
#define NC 32
#define LC 64
#define UROWB 8768  // u row stride in bytes (4384 * 2)

__device__ __forceinline__ void gload_lds16(const void* g, void* l) {
  __builtin_amdgcn_global_load_lds(
      (__attribute__((address_space(1))) void*)g,
      (__attribute__((address_space(3))) void*)l, 16, 0, 0);
}

template <int N>
__device__ __forceinline__ void vm_wait() {
  asm volatile("s_waitcnt vmcnt(%0)" ::"n"(N) : "memory");
}
__device__ __forceinline__ void bar() { asm volatile("s_barrier" ::: "memory"); }
__device__ __forceinline__ void lgkm0() {
  asm volatile("s_waitcnt lgkmcnt(0)" ::: "memory");
}
__device__ __forceinline__ float fsilu(float v) {
  return v * __builtin_amdgcn_rcpf(1.f + __expf(-v));
}

// ---------------- both weight transposes in one launch (z selects which)
__global__ void transpose_both(const float* __restrict__ W0, bf16* __restrict__ T0,
                               const float* __restrict__ W1, bf16* __restrict__ T1,
                               const float* __restrict__ rw1) {
  const float* W; bf16* WT; int K, N, Npad; const float* rw;
  if (blockIdx.z == 0) { W = W0; WT = T0; K = 1024; N = DPROJ; Npad = NPAD1; rw = nullptr; }
  else { W = W1; WT = T1; K = DIN; N = DM; Npad = DM; rw = rw1; }
  int k0 = blockIdx.x * 32, n0 = blockIdx.y * 32;
  if (k0 >= K || n0 >= Npad) return;  // block-uniform exit, no sync hazard
  __shared__ float tile[32][33];
  int tx = threadIdx.x, ty = threadIdx.y;  // (32, 8)
#pragma unroll
  for (int j = 0; j < 4; j++) {
    int k = k0 + ty + 8 * j, n = n0 + tx;
    float v = (k < K && n < N) ? W[(size_t)k * N + n] : 0.f;
    if (rw && k < K) v *= rw[k];
    tile[ty + 8 * j][tx] = v;
  }
  __syncthreads();
#pragma unroll
  for (int j = 0; j < 4; j++) {
    int n = n0 + ty + 8 * j, k = k0 + tx;
    if (n < Npad && k < K) WT[(size_t)n * K + k] = (bf16)tile[tx][ty + 8 * j];
  }
}

// ---------------- layernorm (f32 in) -> xn bf16
__global__ __launch_bounds__(256) void ln_kernel(const float* __restrict__ x,
                                                 const float* __restrict__ lw,
                                                 const float* __restrict__ lb,
                                                 bf16* __restrict__ xn) {
  int row = blockIdx.x;
  int t = threadIdx.x;
  f32x4 v4 = ((const f32x4*)(x + (size_t)row * DM))[t];
  float v0 = v4[0], v1 = v4[1], v2 = v4[2], v3 = v4[3];
  float s = v0 + v1 + v2 + v3;
  float s2 = v0 * v0 + v1 * v1 + v2 * v2 + v3 * v3;
#pragma unroll
  for (int off = 32; off > 0; off >>= 1) {
    s += __shfl_down(s, off);
    s2 += __shfl_down(s2, off);
  }
  __shared__ float ps[8];
  int wave = t >> 6, lane = t & 63;
  if (lane == 0) { ps[wave] = s; ps[4 + wave] = s2; }
  __syncthreads();
  s = ps[0] + ps[1] + ps[2] + ps[3];
  s2 = ps[4] + ps[5] + ps[6] + ps[7];
  float mean = s * (1.f / DM);
  float var = s2 * (1.f / DM) - mean * mean;
  float rstd = rsqrtf(var + 1e-5f);
  f32x4 wv = ((const f32x4*)lw)[t];
  f32x4 bv = ((const f32x4*)lb)[t];
  bf16 o[4];
  o[0] = (bf16)((v0 - mean) * rstd * wv[0] + bv[0]);
  o[1] = (bf16)((v1 - mean) * rstd * wv[1] + bv[1]);
  o[2] = (bf16)((v2 - mean) * rstd * wv[2] + bv[2]);
  o[3] = (bf16)((v3 - mean) * rstd * wv[3] + bv[3]);
  bf16* dst = xn + (size_t)row * DM + t * 4;
  dst[0] = o[0]; dst[1] = o[1]; dst[2] = o[2]; dst[3] = o[3];
}

// ---------------- GEMM1: 128x192 tile, grid 1536 (= 3 rounds at 2 blocks/CU), BK=64,
// 8 waves (2M x 4N, wave 64x48). LDS 80KB -> 2 blocks/CU (m114 inter-block overlap).
__global__ __launch_bounds__(512, 2) void gemm1_8p(const bf16* __restrict__ A,
                                                   const bf16* __restrict__ BT,
                                                   bf16* __restrict__ C) {
  __shared__ char lds[81920];
  int bid = blockIdx.x;  // 1536 = 64 m-tiles * 24 n-tiles
  int xcd = bid & 7;
  int l = bid >> 3;             // 0..191
  int bm = xcd * 8 + (l & 7);
  int bn = l >> 3;
  int m0 = bm * 128, n0 = bn * 192;
  int t = threadIdx.x, lane = t & 63, wave = t >> 6;
  int wm = wave >> 2, wn = wave & 3;
  int lr16 = lane & 15, kq = lane >> 4;
  int ts0 = kq ^ (lr16 & 7);
  int ts1 = (4 + kq) ^ (lr16 & 7);
  int sw = (lane & 7) ^ (lane >> 3);
  int l8 = lane >> 3;
  const char* Ab = (const char*)A;
  const char* Bb = (const char*)BT;

  auto stA = [&](int kt) {
    char* slot = lds + (kt & 1) * 16384;
    size_t ko = (size_t)kt * 128 + sw * 16;
#pragma unroll
    for (int g = 0; g < 2; g++) {
      int c = wave * 2 + g;
      gload_lds16(Ab + (size_t)(m0 + c * 8 + l8) * 2048 + ko, slot + c * 1024);
    }
  };
  auto stB = [&](int kt) {
    char* slot = lds + 32768 + (kt & 1) * 24576;
    size_t ko = (size_t)kt * 128 + sw * 16;
#pragma unroll
    for (int g = 0; g < 3; g++) {
      int c = wave * 3 + g;
      gload_lds16(Bb + (size_t)(n0 + c * 8 + l8) * 2048 + ko, slot + c * 1024);
    }
  };

  f32x4 acc[4][3] = {};
  bf16x8 a_[2][2], b_[3][2];

  stA(0); stB(0); stA(1); stB(1);
  vm_wait<5>();
  bar();
#pragma unroll 1
  for (int kt = 0; kt < 16; kt++) {
    const char* sa = lds + (kt & 1) * 16384;
    const char* sb = lds + 32768 + (kt & 1) * 24576;
    {
#pragma unroll
      for (int mi = 0; mi < 2; mi++) {
        int lrow = wm * 64 + mi * 16 + lr16;
        a_[mi][0] = *(const bf16x8*)(sa + lrow * 128 + ts0 * 16);
        a_[mi][1] = *(const bf16x8*)(sa + lrow * 128 + ts1 * 16);
      }
#pragma unroll
      for (int ni = 0; ni < 3; ni++) {
        int lrow = wn * 48 + ni * 16 + lr16;
        b_[ni][0] = *(const bf16x8*)(sb + lrow * 128 + ts0 * 16);
        b_[ni][1] = *(const bf16x8*)(sb + lrow * 128 + ts1 * 16);
      }
      if (kt >= 1 && kt < 15) { stA(kt + 1); stB(kt + 1); }
      bar();
      lgkm0();
      __builtin_amdgcn_s_setprio(1);
#pragma unroll
      for (int mi = 0; mi < 2; mi++)
#pragma unroll
        for (int ni = 0; ni < 3; ni++) {
          acc[mi][ni] = __builtin_amdgcn_mfma_f32_16x16x32_bf16(a_[mi][0], b_[ni][0], acc[mi][ni], 0, 0, 0);
          acc[mi][ni] = __builtin_amdgcn_mfma_f32_16x16x32_bf16(a_[mi][1], b_[ni][1], acc[mi][ni], 0, 0, 0);
        }
      __builtin_amdgcn_s_setprio(0);
      bar();
    }
    {
#pragma unroll
      for (int mi = 0; mi < 2; mi++) {
        int lrow = wm * 64 + (2 + mi) * 16 + lr16;
        a_[mi][0] = *(const bf16x8*)(sa + lrow * 128 + ts0 * 16);
        a_[mi][1] = *(const bf16x8*)(sa + lrow * 128 + ts1 * 16);
      }
      if (kt < 15) vm_wait<0>();
      bar();
      lgkm0();
      __builtin_amdgcn_s_setprio(1);
#pragma unroll
      for (int mi = 0; mi < 2; mi++)
#pragma unroll
        for (int ni = 0; ni < 3; ni++) {
          acc[2 + mi][ni] = __builtin_amdgcn_mfma_f32_16x16x32_bf16(a_[mi][0], b_[ni][0], acc[2 + mi][ni], 0, 0, 0);
          acc[2 + mi][ni] = __builtin_amdgcn_mfma_f32_16x16x32_bf16(a_[mi][1], b_[ni][1], acc[2 + mi][ni], 0, 0, 0);
        }
      __builtin_amdgcn_s_setprio(0);
      bar();
    }
  }
#pragma unroll
  for (int fr = 0; fr < 4; fr++)
#pragma unroll
    for (int ni = 0; ni < 3; ni++) {
      int row = m0 + wm * 64 + fr * 16 + kq * 4;
      int col = n0 + wn * 48 + ni * 16 + lr16;
      f32x4 v = acc[fr][ni];
      if (col < 4384) {
#pragma unroll
        for (int r = 0; r < 4; r++)
          C[(size_t)(row + r) * DPROJ + col] = (bf16)v[r];
      }
    }
}

// ---------------- GEMM2: 128x256 tile, BK=64, 8 waves (2M x 4N), grid 256.
// A = g_raw; fused RMSNorm (rms_w folded into WoutT; s2 from A-fragments).
__global__ __launch_bounds__(512, 2) void gemm2_8p(const bf16* __restrict__ A,
                                                   const bf16* __restrict__ BT,
                                                   float* __restrict__ C,
                                                   const float* __restrict__ Xres) {
  __shared__ char lds[147456];
  int bid = blockIdx.x;                  // 256 = 64 m * 4 n
  int swz = (bid & 7) * 32 + (bid >> 3); // bijective (256 % 8 == 0)
  int bm = swz >> 2, bn = swz & 3;
  int m0 = bm * 128, n0 = bn * 256;
  int t = threadIdx.x, lane = t & 63, wave = t >> 6;
  int wm = wave >> 2, wn = wave & 3;
  int lr16 = lane & 15, kq = lane >> 4;
  int ts0 = kq ^ (lr16 & 7);
  int ts1 = (4 + kq) ^ (lr16 & 7);
  int sw = (lane & 7) ^ (lane >> 3);
  int l8 = lane >> 3;
  const char* Ab = (const char*)A;
  const char* Bb = (const char*)BT;

  auto stA = [&](int kt) {
    char* slot = lds + (kt % 3) * 16384;
    size_t ko = (size_t)kt * 128 + sw * 16;
#pragma unroll
    for (int g = 0; g < 2; g++) {
      int c = wave * 2 + g;
      gload_lds16(Ab + (size_t)(m0 + c * 8 + l8) * 4096 + ko, slot + c * 1024);
    }
  };
  auto stB = [&](int kt) {
    char* slot = lds + 49152 + (kt % 3) * 32768;
    size_t ko = (size_t)kt * 128 + sw * 16;
#pragma unroll
    for (int g = 0; g < 4; g++) {
      int c = wave * 4 + g;
      gload_lds16(Bb + (size_t)(n0 + c * 8 + l8) * 4096 + ko, slot + c * 1024);
    }
  };

  f32x4 acc[4][4] = {};
  bf16x8 a_[4][2], b_[2][2];
  float s2a[4] = {0.f, 0.f, 0.f, 0.f};

  stA(0); stB(0); stA(1); stB(1);
  vm_wait<6>();
  bar();
#pragma unroll 1
  for (int kt = 0; kt < 32; kt++) {
    const char* sa = lds + (kt % 3) * 16384;
    const char* sb = lds + 49152 + (kt % 3) * 32768;
    {
#pragma unroll
      for (int mi = 0; mi < 4; mi++) {
        int lrow = wm * 64 + mi * 16 + lr16;
        a_[mi][0] = *(const bf16x8*)(sa + lrow * 128 + ts0 * 16);
        a_[mi][1] = *(const bf16x8*)(sa + lrow * 128 + ts1 * 16);
      }
#pragma unroll
      for (int ni = 0; ni < 2; ni++) {
        int lrow = wn * 64 + ni * 16 + lr16;
        b_[ni][0] = *(const bf16x8*)(sb + lrow * 128 + ts0 * 16);
        b_[ni][1] = *(const bf16x8*)(sb + lrow * 128 + ts1 * 16);
      }
      if (kt + 2 < 32) { stA(kt + 2); stB(kt + 2); }
      bar();
      lgkm0();
      __builtin_amdgcn_s_setprio(1);
#pragma unroll
      for (int mi = 0; mi < 4; mi++)
#pragma unroll
        for (int ni = 0; ni < 2; ni++) {
          acc[mi][ni] = __builtin_amdgcn_mfma_f32_16x16x32_bf16(a_[mi][0], b_[ni][0], acc[mi][ni], 0, 0, 0);
          acc[mi][ni] = __builtin_amdgcn_mfma_f32_16x16x32_bf16(a_[mi][1], b_[ni][1], acc[mi][ni], 0, 0, 0);
        }
      __builtin_amdgcn_s_setprio(0);
      bar();
    }
    {
#pragma unroll
      for (int ni = 0; ni < 2; ni++) {
        int lrow = wn * 64 + (2 + ni) * 16 + lr16;
        b_[ni][0] = *(const bf16x8*)(sb + lrow * 128 + ts0 * 16);
        b_[ni][1] = *(const bf16x8*)(sb + lrow * 128 + ts1 * 16);
      }
      if (kt <= 29) vm_wait<6>();
      else if (kt == 30) vm_wait<0>();
      bar();
      lgkm0();
      __builtin_amdgcn_s_setprio(1);
#pragma unroll
      for (int mi = 0; mi < 4; mi++)
#pragma unroll
        for (int ni = 0; ni < 2; ni++) {
          acc[mi][2 + ni] = __builtin_amdgcn_mfma_f32_16x16x32_bf16(a_[mi][0], b_[ni][0], acc[mi][2 + ni], 0, 0, 0);
          acc[mi][2 + ni] = __builtin_amdgcn_mfma_f32_16x16x32_bf16(a_[mi][1], b_[ni][1], acc[mi][2 + ni], 0, 0, 0);
        }
      __builtin_amdgcn_s_setprio(0);
#pragma unroll
      for (int mi = 0; mi < 4; mi++) {
        float s = 0.f;
#pragma unroll
        for (int si = 0; si < 2; si++)
#pragma unroll
          for (int e = 0; e < 8; e++) {
            float v = (float)a_[mi][si][e];
            s += v * v;
          }
        s2a[mi] += s;
      }
      bar();
    }
  }
#pragma unroll
  for (int mi = 0; mi < 4; mi++) {
    s2a[mi] += __shfl_xor(s2a[mi], 16);
    s2a[mi] += __shfl_xor(s2a[mi], 32);
  }
  float* scaleL = (float*)lds;
  if (wn == 0 && kq == 0) {
#pragma unroll
    for (int mi = 0; mi < 4; mi++)
      scaleL[wm * 64 + mi * 16 + lr16] = rsqrtf(s2a[mi] * (1.f / 2048.f) + 1e-5f);
  }
  __syncthreads();
#pragma unroll
  for (int mi = 0; mi < 4; mi++)
#pragma unroll
    for (int ni = 0; ni < 4; ni++) {
      int rloc = wm * 64 + mi * 16 + kq * 4;
      int col = n0 + wn * 64 + ni * 16 + lr16;
      f32x4 v = acc[mi][ni];
#pragma unroll
      for (int r = 0; r < 4; r++) {
        float sc = scaleL[rloc + r];
        size_t o = (size_t)(m0 + rloc + r) * DM + col;
        C[o] = Xres[o] + sc * v[r];
      }
    }
}

// ---------------- conv: one thread per 8-channel vector per row (wide precompute)
__global__ __launch_bounds__(256) void conv_prep3(const bf16* __restrict__ u,
                                                  const float* __restrict__ cw,
                                                  const float* __restrict__ cb,
                                                  const float* __restrict__ dt_bias,
                                                  bf16* __restrict__ xs,
                                                  float* __restrict__ BC,
                                                  float* __restrict__ dtf) {
  const int JPR = 292;  // 260 conv vec8 + 32 dt vec8
  int idx = blockIdx.x * 256 + threadIdx.x;
  if (idx >= MROWS * JPR) return;
  int row = idx / JPR;
  int j = idx - row * JPR;
  int t = row & (SEQ - 1);
  if (j < 260) {
    int c0 = j * 8;
    float acc[8];
#pragma unroll
    for (int i = 0; i < 8; i++) acc[i] = cb[c0 + i];
    const bf16* ub = u + (size_t)row * DPROJ + DIN + c0;
#pragma unroll
    for (int tap = 0; tap < 4; tap++) {
      int tt = t - 3 + tap;
      if (tt >= 0) {
        bf16x8 uv = *(const bf16x8*)(ub + (ptrdiff_t)(tap - 3) * DPROJ);
        const float* wv = cw + tap * CONVD + c0;
#pragma unroll
        for (int i = 0; i < 8; i++) acc[i] += wv[i] * (float)uv[i];
      }
    }
    if (c0 < DIN) {
      bf16x8 o;
#pragma unroll
      for (int i = 0; i < 8; i++) o[i] = (bf16)fsilu(acc[i]);
      *(bf16x8*)(xs + (size_t)row * DIN + c0) = o;
    } else {
      float* bc = BC + (size_t)row * 32 + (c0 - DIN);
#pragma unroll
      for (int i = 0; i < 8; i++) bc[i] = fsilu(acc[i]);
    }
  } else {
    int h0 = (j - 260) * 8;
    bf16x8 uv = *(const bf16x8*)(u + (size_t)row * DPROJ + (DPROJ - NH) + h0);
    float* dst = dtf + (size_t)row * NH + h0;
#pragma unroll
    for (int i = 0; i < 8; i++) {
      float xv = (float)uv[i] + dt_bias[h0 + i];
      dst[i] = (xv > 20.f) ? xv : log1pf(__expf(xv));
    }
  }
}

// ---------------- chunked scan (LC=64, NC=32), phase 1: local scan -> (S, P) in u tail
__global__ __launch_bounds__(64) void scan_p1(const bf16* __restrict__ xs,
                                              const float* __restrict__ BC,
                                              const float* __restrict__ dtf,
                                              const float* __restrict__ A_log,
                                              bf16* __restrict__ uscr) {
  int c = blockIdx.x & 31, hg = (blockIdx.x >> 5) & 31, b = blockIdx.x >> 10;
  int lane = threadIdx.x, hh = lane >> 3;
  int h = hg * 8 + hh;
  float A = -__expf(A_log[h]);
  float st[16];
#pragma unroll
  for (int n = 0; n < 16; n++) st[n] = 0.f;
  float pcum = 1.f;
  size_t rb = (size_t)b * SEQ + (size_t)c * LC;
#pragma unroll 2
  for (int t = 0; t < LC; t++) {
    size_t row = rb + t;
    const f32x4* bc4 = (const f32x4*)(BC + row * 32);
    f32x4 bv[4], cv[4];
#pragma unroll
    for (int q = 0; q < 4; q++) bv[q] = bc4[q];
#pragma unroll
    for (int q = 0; q < 4; q++) cv[q] = bc4[4 + q];
    float dtv = dtf[row * NH + h];
    float x = (float)xs[row * DIN + hg * 64 + lane];
    float dA = __expf(dtv * A);
    pcum *= dA;
    float w = dtv * x;
#pragma unroll
    for (int q = 0; q < 4; q++)
#pragma unroll
      for (int e = 0; e < 4; e++)
        st[q * 4 + e] = st[q * 4 + e] * dA + w * bv[q][e];
    (void)cv;
  }
  char* slot = (char*)uscr + (size_t)blockIdx.x * UROWB + 4096;
  float* S = (float*)slot;
#pragma unroll
  for (int n = 0; n < 16; n++) S[lane * 16 + n] = st[n];
  if ((lane & 7) == 0) ((float*)(slot + 4096))[hh] = pcum;
}

// ---------------- phase 2: sequential combine over 32 chunks; S <- incoming H
__global__ __launch_bounds__(64) void scan_p2(bf16* __restrict__ uscr) {
  int bh = blockIdx.x;  // 0..127 = b*32+hg
  int lane = threadIdx.x, hh = lane >> 3;
  float H[16];
#pragma unroll
  for (int n = 0; n < 16; n++) H[n] = 0.f;
  char* base = (char*)uscr + (size_t)bh * NC * UROWB + 4096;
  float sN[16], PN;
  {
    float* S = (float*)base;
#pragma unroll
    for (int n = 0; n < 16; n++) sN[n] = S[lane * 16 + n];
    PN = ((const float*)(base + 4096))[hh];
  }
  for (int c = 0; c < NC; c++) {
    float sC[16], PC = PN;
#pragma unroll
    for (int n = 0; n < 16; n++) sC[n] = sN[n];
    if (c + 1 < NC) {
      char* slot = base + (size_t)(c + 1) * UROWB;
      float* S = (float*)slot;
#pragma unroll
      for (int n = 0; n < 16; n++) sN[n] = S[lane * 16 + n];
      PN = ((const float*)(slot + 4096))[hh];
    }
    float* S0 = (float*)(base + (size_t)c * UROWB);
#pragma unroll
    for (int n = 0; n < 16; n++) {
      float hn = H[n];
      S0[lane * 16 + n] = hn;
      H[n] = PC * hn + sC[n];
    }
  }
}

// ---------------- phase 3 (fused gate): re-scan chunk, g_raw = (yv + D*x)*silu(z)
__global__ __launch_bounds__(64) void scan_p3(const bf16* __restrict__ xs,
                                              const float* __restrict__ BC,
                                              const float* __restrict__ dtf,
                                              const float* __restrict__ A_log,
                                              const float* __restrict__ Dp,
                                              const bf16* __restrict__ u,
                                              bf16* __restrict__ g) {
  int c = blockIdx.x & 31, hg = (blockIdx.x >> 5) & 31, b = blockIdx.x >> 10;
  int lane = threadIdx.x, hh = lane >> 3;
  int h = hg * 8 + hh;
  float A = -__expf(A_log[h]);
  float D = Dp[h];
  const char* slot = (const char*)u + (size_t)blockIdx.x * UROWB + 4096;
  float st[16];
#pragma unroll
  for (int n = 0; n < 16; n++) st[n] = ((const float*)slot)[lane * 16 + n];
  size_t rb = (size_t)b * SEQ + (size_t)c * LC;
#pragma unroll 2
  for (int t = 0; t < LC; t++) {
    size_t row = rb + t;
    const f32x4* bc4 = (const f32x4*)(BC + row * 32);
    f32x4 bv[4], cv[4];
#pragma unroll
    for (int q = 0; q < 4; q++) bv[q] = bc4[q];
#pragma unroll
    for (int q = 0; q < 4; q++) cv[q] = bc4[4 + q];
    float dtv = dtf[row * NH + h];
    float x = (float)xs[row * DIN + hg * 64 + lane];
    float dA = __expf(dtv * A);
    float w = dtv * x;
    float yv = 0.f;
#pragma unroll
    for (int q = 0; q < 4; q++)
#pragma unroll
      for (int e = 0; e < 4; e++) {
        int n = q * 4 + e;
        st[n] = st[n] * dA + w * bv[q][e];
        yv += st[n] * cv[q][e];
      }
    float z = (float)u[row * DPROJ + hg * 64 + lane];
    float gg = (yv + D * x) * fsilu(z);
    g[row * DIN + hg * 64 + lane] = (bf16)gg;
  }
}

extern "C" void kernel_launch(void* const* d_in, const int* in_sizes, int n_in,
                              void* d_out, int out_size, void* d_ws, size_t ws_size,
                              hipStream_t stream) {
  const float* x = (const float*)d_in[0];
  const float* lnw = (const float*)d_in[1];
  const float* lnb = (const float*)d_in[2];
  const float* Win = (const float*)d_in[3];
  const float* cw = (const float*)d_in[4];
  const float* cb = (const float*)d_in[5];
  const float* Alog = (const float*)d_in[6];
  const float* Dpv = (const float*)d_in[7];
  const float* dtb = (const float*)d_in[8];
  const float* rmsw = (const float*)d_in[9];
  const float* Wout = (const float*)d_in[10];
  float* out = (float*)d_out;

  char* ws = (char*)d_ws;
  bf16* u = (bf16*)(ws + 0);                     // [8192][4384] bf16
  bf16* xnb = (bf16*)(ws + 71827456);            // [8192][1024] bf16 (dead after GEMM1)
  bf16* WinT = (bf16*)(ws + 88604672);           // [4608][1024] bf16 (dead after GEMM1)
  bf16* gb = (bf16*)(ws + 71827456);             // [8192][2048] bf16 g_raw (reuses xnb+WinT)
  bf16* xsb = (bf16*)(ws + 105381888);           // [8192][2048] bf16
  float* BC = (float*)(ws + 138936320);          // [8192][32] f32
  float* dtf = (float*)(ws + 139984896);         // [8192][256] f32
  bf16* WoutT = (bf16*)(ws + 148373504);         // [1024][2048] bf16 (rms_w folded)

  transpose_both<<<dim3(64, 144, 2), dim3(32, 8), 0, stream>>>(Win, WinT, Wout, WoutT, rmsw);
  ln_kernel<<<MROWS, 256, 0, stream>>>(x, lnw, lnb, xnb);
  gemm1_8p<<<1536, 512, 0, stream>>>(xnb, WinT, u);
  conv_prep3<<<(MROWS * 292) / 256, 256, 0, stream>>>(u, cw, cb, dtb, xsb, BC, dtf);
  scan_p1<<<4096, 64, 0, stream>>>(xsb, BC, dtf, Alog, u);
  scan_p2<<<128, 64, 0, stream>>>(u);
  scan_p3<<<4096, 64, 0, stream>>>(xsb, BC, dtf, Alog, Dpv, u, gb);
  gemm2_8p<<<256, 512, 0, stream>>>(gb, WoutT, out, x);
}

// Round 23
// 275.699 us; speedup vs baseline: 1.2445x; 1.0062x over previous
//
#include <hip/hip_runtime.h>

typedef __bf16 bf16;
typedef __attribute__((ext_vector_type(8))) __bf16 bf16x8;
typedef __attribute__((ext_vector_type(4))) float f32x4;

#define B_SZ 4
#define SEQ 2048
#define DM 1024
#define DIN 2048
#define NH 256
#define DSTATE 16
#define CONVD 2080
#define DPROJ 4384
#define NPAD1 4608
#define MROWS 8192
#define NC 32
#define LC 64
#define UROWB 8768  // u row stride in bytes (4384 * 2)

__device__ __forceinline__ void gload_lds16(const void* g, void* l) {
  __builtin_amdgcn_global_load_lds(
      (__attribute__((address_space(1))) void*)g,
      (__attribute__((address_space(3))) void*)l, 16, 0, 0);
}

template <int N>
__device__ __forceinline__ void vm_wait() {
  asm volatile("s_waitcnt vmcnt(%0)" ::"n"(N) : "memory");
}
__device__ __forceinline__ void bar() { asm volatile("s_barrier" ::: "memory"); }
__device__ __forceinline__ void lgkm0() {
  asm volatile("s_waitcnt lgkmcnt(0)" ::: "memory");
}
__device__ __forceinline__ float fsilu(float v) {
  return v * __builtin_amdgcn_rcpf(1.f + __expf(-v));
}

// ---------------- prep: z=0/1 weight transposes, z=2 layernorm (all 256-thr blocks)
__global__ void prep_kernel(const float* __restrict__ W0, bf16* __restrict__ T0,
                            const float* __restrict__ W1, bf16* __restrict__ T1,
                            const float* __restrict__ rw1,
                            const float* __restrict__ x, const float* __restrict__ lw,
                            const float* __restrict__ lb, bf16* __restrict__ xn) {
  if (blockIdx.z < 2) {
    const float* W; bf16* WT; int K, N, Npad; const float* rw;
    if (blockIdx.z == 0) { W = W0; WT = T0; K = 1024; N = DPROJ; Npad = NPAD1; rw = nullptr; }
    else { W = W1; WT = T1; K = DIN; N = DM; Npad = DM; rw = rw1; }
    int k0 = blockIdx.x * 32, n0 = blockIdx.y * 32;
    if (k0 >= K || n0 >= Npad) return;  // block-uniform exit
    __shared__ float tile[32][33];
    int tx = threadIdx.x, ty = threadIdx.y;  // (32, 8)
#pragma unroll
    for (int j = 0; j < 4; j++) {
      int k = k0 + ty + 8 * j, n = n0 + tx;
      float v = (k < K && n < N) ? W[(size_t)k * N + n] : 0.f;
      if (rw && k < K) v *= rw[k];
      tile[ty + 8 * j][tx] = v;
    }
    __syncthreads();
#pragma unroll
    for (int j = 0; j < 4; j++) {
      int n = n0 + ty + 8 * j, k = k0 + tx;
      if (n < Npad && k < K) WT[(size_t)n * K + k] = (bf16)tile[tx][ty + 8 * j];
    }
    return;
  }
  // ---- z == 2: layernorm; row = by*64 + bx
  int row = blockIdx.y * 64 + blockIdx.x;
  if (row >= MROWS) return;  // block-uniform
  int t = threadIdx.y * 32 + threadIdx.x;
  f32x4 v4 = ((const f32x4*)(x + (size_t)row * DM))[t];
  float v0 = v4[0], v1 = v4[1], v2 = v4[2], v3 = v4[3];
  float s = v0 + v1 + v2 + v3;
  float s2 = v0 * v0 + v1 * v1 + v2 * v2 + v3 * v3;
#pragma unroll
  for (int off = 32; off > 0; off >>= 1) {
    s += __shfl_down(s, off);
    s2 += __shfl_down(s2, off);
  }
  __shared__ float ps[8];
  int wave = t >> 6, lane = t & 63;
  if (lane == 0) { ps[wave] = s; ps[4 + wave] = s2; }
  __syncthreads();
  s = ps[0] + ps[1] + ps[2] + ps[3];
  s2 = ps[4] + ps[5] + ps[6] + ps[7];
  float mean = s * (1.f / DM);
  float var = s2 * (1.f / DM) - mean * mean;
  float rstd = rsqrtf(var + 1e-5f);
  f32x4 wv = ((const f32x4*)lw)[t];
  f32x4 bv = ((const f32x4*)lb)[t];
  bf16 o[4];
  o[0] = (bf16)((v0 - mean) * rstd * wv[0] + bv[0]);
  o[1] = (bf16)((v1 - mean) * rstd * wv[1] + bv[1]);
  o[2] = (bf16)((v2 - mean) * rstd * wv[2] + bv[2]);
  o[3] = (bf16)((v3 - mean) * rstd * wv[3] + bv[3]);
  bf16* dst = xn + (size_t)row * DM + t * 4;
  dst[0] = o[0]; dst[1] = o[1]; dst[2] = o[2]; dst[3] = o[3];
}

// ---------------- GEMM1: 128x192 tile, grid 1536 (= 3 rounds at 2 blocks/CU), BK=64,
// 8 waves (2M x 4N, wave 64x48). LDS 80KB -> 2 blocks/CU (m114 inter-block overlap).
__global__ __launch_bounds__(512, 2) void gemm1_8p(const bf16* __restrict__ A,
                                                   const bf16* __restrict__ BT,
                                                   bf16* __restrict__ C) {
  __shared__ char lds[81920];
  int bid = blockIdx.x;  // 1536 = 64 m-tiles * 24 n-tiles
  int xcd = bid & 7;
  int l = bid >> 3;             // 0..191
  int bm = xcd * 8 + (l & 7);
  int bn = l >> 3;
  int m0 = bm * 128, n0 = bn * 192;
  int t = threadIdx.x, lane = t & 63, wave = t >> 6;
  int wm = wave >> 2, wn = wave & 3;
  int lr16 = lane & 15, kq = lane >> 4;
  int ts0 = kq ^ (lr16 & 7);
  int ts1 = (4 + kq) ^ (lr16 & 7);
  int sw = (lane & 7) ^ (lane >> 3);
  int l8 = lane >> 3;
  const char* Ab = (const char*)A;
  const char* Bb = (const char*)BT;

  auto stA = [&](int kt) {
    char* slot = lds + (kt & 1) * 16384;
    size_t ko = (size_t)kt * 128 + sw * 16;
#pragma unroll
    for (int g = 0; g < 2; g++) {
      int c = wave * 2 + g;
      gload_lds16(Ab + (size_t)(m0 + c * 8 + l8) * 2048 + ko, slot + c * 1024);
    }
  };
  auto stB = [&](int kt) {
    char* slot = lds + 32768 + (kt & 1) * 24576;
    size_t ko = (size_t)kt * 128 + sw * 16;
#pragma unroll
    for (int g = 0; g < 3; g++) {
      int c = wave * 3 + g;
      gload_lds16(Bb + (size_t)(n0 + c * 8 + l8) * 2048 + ko, slot + c * 1024);
    }
  };

  f32x4 acc[4][3] = {};
  bf16x8 a_[2][2], b_[3][2];

  stA(0); stB(0); stA(1); stB(1);
  vm_wait<5>();
  bar();
#pragma unroll 1
  for (int kt = 0; kt < 16; kt++) {
    const char* sa = lds + (kt & 1) * 16384;
    const char* sb = lds + 32768 + (kt & 1) * 24576;
    {
#pragma unroll
      for (int mi = 0; mi < 2; mi++) {
        int lrow = wm * 64 + mi * 16 + lr16;
        a_[mi][0] = *(const bf16x8*)(sa + lrow * 128 + ts0 * 16);
        a_[mi][1] = *(const bf16x8*)(sa + lrow * 128 + ts1 * 16);
      }
#pragma unroll
      for (int ni = 0; ni < 3; ni++) {
        int lrow = wn * 48 + ni * 16 + lr16;
        b_[ni][0] = *(const bf16x8*)(sb + lrow * 128 + ts0 * 16);
        b_[ni][1] = *(const bf16x8*)(sb + lrow * 128 + ts1 * 16);
      }
      if (kt >= 1 && kt < 15) { stA(kt + 1); stB(kt + 1); }
      bar();
      lgkm0();
      __builtin_amdgcn_s_setprio(1);
#pragma unroll
      for (int mi = 0; mi < 2; mi++)
#pragma unroll
        for (int ni = 0; ni < 3; ni++) {
          acc[mi][ni] = __builtin_amdgcn_mfma_f32_16x16x32_bf16(a_[mi][0], b_[ni][0], acc[mi][ni], 0, 0, 0);
          acc[mi][ni] = __builtin_amdgcn_mfma_f32_16x16x32_bf16(a_[mi][1], b_[ni][1], acc[mi][ni], 0, 0, 0);
        }
      __builtin_amdgcn_s_setprio(0);
      bar();
    }
    {
#pragma unroll
      for (int mi = 0; mi < 2; mi++) {
        int lrow = wm * 64 + (2 + mi) * 16 + lr16;
        a_[mi][0] = *(const bf16x8*)(sa + lrow * 128 + ts0 * 16);
        a_[mi][1] = *(const bf16x8*)(sa + lrow * 128 + ts1 * 16);
      }
      if (kt < 15) vm_wait<0>();
      bar();
      lgkm0();
      __builtin_amdgcn_s_setprio(1);
#pragma unroll
      for (int mi = 0; mi < 2; mi++)
#pragma unroll
        for (int ni = 0; ni < 3; ni++) {
          acc[2 + mi][ni] = __builtin_amdgcn_mfma_f32_16x16x32_bf16(a_[mi][0], b_[ni][0], acc[2 + mi][ni], 0, 0, 0);
          acc[2 + mi][ni] = __builtin_amdgcn_mfma_f32_16x16x32_bf16(a_[mi][1], b_[ni][1], acc[2 + mi][ni], 0, 0, 0);
        }
      __builtin_amdgcn_s_setprio(0);
      bar();
    }
  }
#pragma unroll
  for (int fr = 0; fr < 4; fr++)
#pragma unroll
    for (int ni = 0; ni < 3; ni++) {
      int row = m0 + wm * 64 + fr * 16 + kq * 4;
      int col = n0 + wn * 48 + ni * 16 + lr16;
      f32x4 v = acc[fr][ni];
      if (col < 4384) {
#pragma unroll
        for (int r = 0; r < 4; r++)
          C[(size_t)(row + r) * DPROJ + col] = (bf16)v[r];
      }
    }
}

// ---------------- GEMM2: 128x256 tile, BK=64, 8 waves (2M x 4N), grid 256.
// A = g_raw; fused RMSNorm (rms_w folded into WoutT; s2 from A-fragments).
__global__ __launch_bounds__(512, 2) void gemm2_8p(const bf16* __restrict__ A,
                                                   const bf16* __restrict__ BT,
                                                   float* __restrict__ C,
                                                   const float* __restrict__ Xres) {
  __shared__ char lds[147456];
  int bid = blockIdx.x;                  // 256 = 64 m * 4 n
  int swz = (bid & 7) * 32 + (bid >> 3); // bijective (256 % 8 == 0)
  int bm = swz >> 2, bn = swz & 3;
  int m0 = bm * 128, n0 = bn * 256;
  int t = threadIdx.x, lane = t & 63, wave = t >> 6;
  int wm = wave >> 2, wn = wave & 3;
  int lr16 = lane & 15, kq = lane >> 4;
  int ts0 = kq ^ (lr16 & 7);
  int ts1 = (4 + kq) ^ (lr16 & 7);
  int sw = (lane & 7) ^ (lane >> 3);
  int l8 = lane >> 3;
  const char* Ab = (const char*)A;
  const char* Bb = (const char*)BT;

  auto stA = [&](int kt) {
    char* slot = lds + (kt % 3) * 16384;
    size_t ko = (size_t)kt * 128 + sw * 16;
#pragma unroll
    for (int g = 0; g < 2; g++) {
      int c = wave * 2 + g;
      gload_lds16(Ab + (size_t)(m0 + c * 8 + l8) * 4096 + ko, slot + c * 1024);
    }
  };
  auto stB = [&](int kt) {
    char* slot = lds + 49152 + (kt % 3) * 32768;
    size_t ko = (size_t)kt * 128 + sw * 16;
#pragma unroll
    for (int g = 0; g < 4; g++) {
      int c = wave * 4 + g;
      gload_lds16(Bb + (size_t)(n0 + c * 8 + l8) * 4096 + ko, slot + c * 1024);
    }
  };

  f32x4 acc[4][4] = {};
  bf16x8 a_[4][2], b_[2][2];
  float s2a[4] = {0.f, 0.f, 0.f, 0.f};

  stA(0); stB(0); stA(1); stB(1);
  vm_wait<6>();
  bar();
#pragma unroll 1
  for (int kt = 0; kt < 32; kt++) {
    const char* sa = lds + (kt % 3) * 16384;
    const char* sb = lds + 49152 + (kt % 3) * 32768;
    {
#pragma unroll
      for (int mi = 0; mi < 4; mi++) {
        int lrow = wm * 64 + mi * 16 + lr16;
        a_[mi][0] = *(const bf16x8*)(sa + lrow * 128 + ts0 * 16);
        a_[mi][1] = *(const bf16x8*)(sa + lrow * 128 + ts1 * 16);
      }
#pragma unroll
      for (int ni = 0; ni < 2; ni++) {
        int lrow = wn * 64 + ni * 16 + lr16;
        b_[ni][0] = *(const bf16x8*)(sb + lrow * 128 + ts0 * 16);
        b_[ni][1] = *(const bf16x8*)(sb + lrow * 128 + ts1 * 16);
      }
      if (kt + 2 < 32) { stA(kt + 2); stB(kt + 2); }
      bar();
      lgkm0();
      __builtin_amdgcn_s_setprio(1);
#pragma unroll
      for (int mi = 0; mi < 4; mi++)
#pragma unroll
        for (int ni = 0; ni < 2; ni++) {
          acc[mi][ni] = __builtin_amdgcn_mfma_f32_16x16x32_bf16(a_[mi][0], b_[ni][0], acc[mi][ni], 0, 0, 0);
          acc[mi][ni] = __builtin_amdgcn_mfma_f32_16x16x32_bf16(a_[mi][1], b_[ni][1], acc[mi][ni], 0, 0, 0);
        }
      __builtin_amdgcn_s_setprio(0);
      bar();
    }
    {
#pragma unroll
      for (int ni = 0; ni < 2; ni++) {
        int lrow = wn * 64 + (2 + ni) * 16 + lr16;
        b_[ni][0] = *(const bf16x8*)(sb + lrow * 128 + ts0 * 16);
        b_[ni][1] = *(const bf16x8*)(sb + lrow * 128 + ts1 * 16);
      }
      if (kt <= 29) vm_wait<6>();
      else if (kt == 30) vm_wait<0>();
      bar();
      lgkm0();
      __builtin_amdgcn_s_setprio(1);
#pragma unroll
      for (int mi = 0; mi < 4; mi++)
#pragma unroll
        for (int ni = 0; ni < 2; ni++) {
          acc[mi][2 + ni] = __builtin_amdgcn_mfma_f32_16x16x32_bf16(a_[mi][0], b_[ni][0], acc[mi][2 + ni], 0, 0, 0);
          acc[mi][2 + ni] = __builtin_amdgcn_mfma_f32_16x16x32_bf16(a_[mi][1], b_[ni][1], acc[mi][2 + ni], 0, 0, 0);
        }
      __builtin_amdgcn_s_setprio(0);
#pragma unroll
      for (int mi = 0; mi < 4; mi++) {
        float s = 0.f;
#pragma unroll
        for (int si = 0; si < 2; si++)
#pragma unroll
          for (int e = 0; e < 8; e++) {
            float v = (float)a_[mi][si][e];
            s += v * v;
          }
        s2a[mi] += s;
      }
      bar();
    }
  }
#pragma unroll
  for (int mi = 0; mi < 4; mi++) {
    s2a[mi] += __shfl_xor(s2a[mi], 16);
    s2a[mi] += __shfl_xor(s2a[mi], 32);
  }
  float* scaleL = (float*)lds;
  if (wn == 0 && kq == 0) {
#pragma unroll
    for (int mi = 0; mi < 4; mi++)
      scaleL[wm * 64 + mi * 16 + lr16] = rsqrtf(s2a[mi] * (1.f / 2048.f) + 1e-5f);
  }
  __syncthreads();
#pragma unroll
  for (int mi = 0; mi < 4; mi++)
#pragma unroll
    for (int ni = 0; ni < 4; ni++) {
      int rloc = wm * 64 + mi * 16 + kq * 4;
      int col = n0 + wn * 64 + ni * 16 + lr16;
      f32x4 v = acc[mi][ni];
#pragma unroll
      for (int r = 0; r < 4; r++) {
        float sc = scaleL[rloc + r];
        size_t o = (size_t)(m0 + rloc + r) * DM + col;
        C[o] = Xres[o] + sc * v[r];
      }
    }
}

// ---------------- conv: one thread per 8-channel vector per row (wide precompute)
__global__ __launch_bounds__(256) void conv_prep3(const bf16* __restrict__ u,
                                                  const float* __restrict__ cw,
                                                  const float* __restrict__ cb,
                                                  const float* __restrict__ dt_bias,
                                                  bf16* __restrict__ xs,
                                                  float* __restrict__ BC,
                                                  float* __restrict__ dtf) {
  const int JPR = 292;  // 260 conv vec8 + 32 dt vec8
  int idx = blockIdx.x * 256 + threadIdx.x;
  if (idx >= MROWS * JPR) return;
  int row = idx / JPR;
  int j = idx - row * JPR;
  int t = row & (SEQ - 1);
  if (j < 260) {
    int c0 = j * 8;
    float acc[8];
#pragma unroll
    for (int i = 0; i < 8; i++) acc[i] = cb[c0 + i];
    const bf16* ub = u + (size_t)row * DPROJ + DIN + c0;
#pragma unroll
    for (int tap = 0; tap < 4; tap++) {
      int tt = t - 3 + tap;
      if (tt >= 0) {
        bf16x8 uv = *(const bf16x8*)(ub + (ptrdiff_t)(tap - 3) * DPROJ);
        const float* wv = cw + tap * CONVD + c0;
#pragma unroll
        for (int i = 0; i < 8; i++) acc[i] += wv[i] * (float)uv[i];
      }
    }
    if (c0 < DIN) {
      bf16x8 o;
#pragma unroll
      for (int i = 0; i < 8; i++) o[i] = (bf16)fsilu(acc[i]);
      *(bf16x8*)(xs + (size_t)row * DIN + c0) = o;
    } else {
      float* bc = BC + (size_t)row * 32 + (c0 - DIN);
#pragma unroll
      for (int i = 0; i < 8; i++) bc[i] = fsilu(acc[i]);
    }
  } else {
    int h0 = (j - 260) * 8;
    bf16x8 uv = *(const bf16x8*)(u + (size_t)row * DPROJ + (DPROJ - NH) + h0);
    float* dst = dtf + (size_t)row * NH + h0;
#pragma unroll
    for (int i = 0; i < 8; i++) {
      float xv = (float)uv[i] + dt_bias[h0 + i];
      dst[i] = (xv > 20.f) ? xv : log1pf(__expf(xv));
    }
  }
}

// ---------------- chunked scan (LC=64, NC=32), phase 1: local scan -> (S, P) in u tail
__global__ __launch_bounds__(64) void scan_p1(const bf16* __restrict__ xs,
                                              const float* __restrict__ BC,
                                              const float* __restrict__ dtf,
                                              const float* __restrict__ A_log,
                                              bf16* __restrict__ uscr) {
  int c = blockIdx.x & 31, hg = (blockIdx.x >> 5) & 31, b = blockIdx.x >> 10;
  int lane = threadIdx.x, hh = lane >> 3;
  int h = hg * 8 + hh;
  float A = -__expf(A_log[h]);
  float st[16];
#pragma unroll
  for (int n = 0; n < 16; n++) st[n] = 0.f;
  float pcum = 1.f;
  size_t rb = (size_t)b * SEQ + (size_t)c * LC;
#pragma unroll 2
  for (int t = 0; t < LC; t++) {
    size_t row = rb + t;
    const f32x4* bc4 = (const f32x4*)(BC + row * 32);
    f32x4 bv[4];
#pragma unroll
    for (int q = 0; q < 4; q++) bv[q] = bc4[q];
    float dtv = dtf[row * NH + h];
    float x = (float)xs[row * DIN + hg * 64 + lane];
    float dA = __expf(dtv * A);
    pcum *= dA;
    float w = dtv * x;
#pragma unroll
    for (int q = 0; q < 4; q++)
#pragma unroll
      for (int e = 0; e < 4; e++)
        st[q * 4 + e] = st[q * 4 + e] * dA + w * bv[q][e];
  }
  char* slot = (char*)uscr + (size_t)blockIdx.x * UROWB + 4096;
  float* S = (float*)slot;
#pragma unroll
  for (int n = 0; n < 16; n++) S[lane * 16 + n] = st[n];
  if ((lane & 7) == 0) ((float*)(slot + 4096))[hh] = pcum;
}

// ---------------- phase 2: sequential combine over 32 chunks; S <- incoming H
__global__ __launch_bounds__(64) void scan_p2(bf16* __restrict__ uscr) {
  int bh = blockIdx.x;  // 0..127 = b*32+hg
  int lane = threadIdx.x, hh = lane >> 3;
  float H[16];
#pragma unroll
  for (int n = 0; n < 16; n++) H[n] = 0.f;
  char* base = (char*)uscr + (size_t)bh * NC * UROWB + 4096;
  float sN[16], PN;
  {
    float* S = (float*)base;
#pragma unroll
    for (int n = 0; n < 16; n++) sN[n] = S[lane * 16 + n];
    PN = ((const float*)(base + 4096))[hh];
  }
  for (int c = 0; c < NC; c++) {
    float sC[16], PC = PN;
#pragma unroll
    for (int n = 0; n < 16; n++) sC[n] = sN[n];
    if (c + 1 < NC) {
      char* slot = base + (size_t)(c + 1) * UROWB;
      float* S = (float*)slot;
#pragma unroll
      for (int n = 0; n < 16; n++) sN[n] = S[lane * 16 + n];
      PN = ((const float*)(slot + 4096))[hh];
    }
    float* S0 = (float*)(base + (size_t)c * UROWB);
#pragma unroll
    for (int n = 0; n < 16; n++) {
      float hn = H[n];
      S0[lane * 16 + n] = hn;
      H[n] = PC * hn + sC[n];
    }
  }
}

// ---------------- phase 3 (fused gate): re-scan chunk, g_raw = (yv + D*x)*silu(z)
__global__ __launch_bounds__(64) void scan_p3(const bf16* __restrict__ xs,
                                              const float* __restrict__ BC,
                                              const float* __restrict__ dtf,
                                              const float* __restrict__ A_log,
                                              const float* __restrict__ Dp,
                                              const bf16* __restrict__ u,
                                              bf16* __restrict__ g) {
  int c = blockIdx.x & 31, hg = (blockIdx.x >> 5) & 31, b = blockIdx.x >> 10;
  int lane = threadIdx.x, hh = lane >> 3;
  int h = hg * 8 + hh;
  float A = -__expf(A_log[h]);
  float D = Dp[h];
  const char* slot = (const char*)u + (size_t)blockIdx.x * UROWB + 4096;
  float st[16];
#pragma unroll
  for (int n = 0; n < 16; n++) st[n] = ((const float*)slot)[lane * 16 + n];
  size_t rb = (size_t)b * SEQ + (size_t)c * LC;
#pragma unroll 2
  for (int t = 0; t < LC; t++) {
    size_t row = rb + t;
    const f32x4* bc4 = (const f32x4*)(BC + row * 32);
    f32x4 bv[4], cv[4];
#pragma unroll
    for (int q = 0; q < 4; q++) bv[q] = bc4[q];
#pragma unroll
    for (int q = 0; q < 4; q++) cv[q] = bc4[4 + q];
    float dtv = dtf[row * NH + h];
    float x = (float)xs[row * DIN + hg * 64 + lane];
    float dA = __expf(dtv * A);
    float w = dtv * x;
    float yv = 0.f;
#pragma unroll
    for (int q = 0; q < 4; q++)
#pragma unroll
      for (int e = 0; e < 4; e++) {
        int n = q * 4 + e;
        st[n] = st[n] * dA + w * bv[q][e];
        yv += st[n] * cv[q][e];
      }
    float z = (float)u[row * DPROJ + hg * 64 + lane];
    float gg = (yv + D * x) * fsilu(z);
    g[row * DIN + hg * 64 + lane] = (bf16)gg;
  }
}

extern "C" void kernel_launch(void* const* d_in, const int* in_sizes, int n_in,
                              void* d_out, int out_size, void* d_ws, size_t ws_size,
                              hipStream_t stream) {
  const float* x = (const float*)d_in[0];
  const float* lnw = (const float*)d_in[1];
  const float* lnb = (const float*)d_in[2];
  const float* Win = (const float*)d_in[3];
  const float* cw = (const float*)d_in[4];
  const float* cb = (const float*)d_in[5];
  const float* Alog = (const float*)d_in[6];
  const float* Dpv = (const float*)d_in[7];
  const float* dtb = (const float*)d_in[8];
  const float* rmsw = (const float*)d_in[9];
  const float* Wout = (const float*)d_in[10];
  float* out = (float*)d_out;

  char* ws = (char*)d_ws;
  bf16* u = (bf16*)(ws + 0);                     // [8192][4384] bf16
  bf16* xnb = (bf16*)(ws + 71827456);            // [8192][1024] bf16 (dead after GEMM1)
  bf16* WinT = (bf16*)(ws + 88604672);           // [4608][1024] bf16 (dead after GEMM1)
  bf16* gb = (bf16*)(ws + 71827456);             // [8192][2048] bf16 g_raw (reuses xnb+WinT)
  bf16* xsb = (bf16*)(ws + 105381888);           // [8192][2048] bf16
  float* BC = (float*)(ws + 138936320);          // [8192][32] f32
  float* dtf = (float*)(ws + 139984896);         // [8192][256] f32
  bf16* WoutT = (bf16*)(ws + 148373504);         // [1024][2048] bf16 (rms_w folded)

  prep_kernel<<<dim3(64, 144, 3), dim3(32, 8), 0, stream>>>(Win, WinT, Wout, WoutT, rmsw,
                                                            x, lnw, lnb, xnb);
  gemm1_8p<<<1536, 512, 0, stream>>>(xnb, WinT, u);
  conv_prep3<<<(MROWS * 292) / 256, 256, 0, stream>>>(u, cw, cb, dtb, xsb, BC, dtf);
  scan_p1<<<4096, 64, 0, stream>>>(xsb, BC, dtf, Alog, u);
  scan_p2<<<128, 64, 0, stream>>>(u);
  scan_p3<<<4096, 64, 0, stream>>>(xsb, BC, dtf, Alog, Dpv, u, gb);
  gemm2_8p<<<256, 512, 0, stream>>>(gb, WoutT, out, x);
}